// Round 4
// baseline (458.863 us; speedup 1.0000x reference)
//
#include <hip/hip_runtime.h>
#include <hip/hip_bf16.h>
#include <stdint.h>

// out = A_sparse @ (X @ W) + b
// CSR build: bucket_hist (bucket-level only) -> tiny scan -> binned_scatter ->
//            local_sort (per-node offsets computed in-LDS, then in-bucket sort).
// GEMM: XWb = X @ W, MFMA 16x16x32 bf16, BM=128 BN=256 (X read exactly once),
//       fp32->bf16 via HW cvt_pk fused into A-staging, 512 threads / 8 waves (2x4).
// Gather: one wave per node, 8B/lane NONTEMPORAL row reads (bypass L2 allocate,
//         serve from L3/MALL), unroll-4, nontemporal out store.

#define D 256             // D_IN == D_OUT == 256
#define EPB 4096          // edges per bucketing block
#define NBUCKET_MAX 512   // supports M <= 131072
#define CPAD 16           // bucket counter padding: one counter per 64B line

typedef __attribute__((ext_vector_type(8))) short bf16x8;
typedef __attribute__((ext_vector_type(4))) float f32x4;
typedef __attribute__((ext_vector_type(4))) unsigned short u16x4;

__device__ __forceinline__ unsigned short f32_to_bf16(float f) {
    union { float f; unsigned int u; } x; x.f = f;
    unsigned int u = x.u;
    u += 0x7fffu + ((u >> 16) & 1u);   // round-to-nearest-even
    return (unsigned short)(u >> 16);
}
__device__ __forceinline__ float bf16_to_f32(unsigned short h) {
    union { unsigned int u; float f; } x; x.u = ((unsigned int)h) << 16;
    return x.f;
}
// pairwise fp32->bf16 RNE via hip_bf16 (lowers to v_cvt_pk_bf16_f32)
__device__ __forceinline__ ushort2 cvt2_bf16(float a, float b) {
    __hip_bfloat162 h = __float22bfloat162_rn(make_float2(a, b));
    union { __hip_bfloat162 h; ushort2 u; } cv; cv.h = h;
    return cv.u;
}

// ---------------- Bucket-level histogram (LDS hist, padded global adds) ----------------

__global__ __launch_bounds__(256) void bucket_hist_kernel(const int* __restrict__ row,
                                                          int* __restrict__ bcount, int E) {
    __shared__ int h[NBUCKET_MAX];
    const int tid = threadIdx.x;
    for (int i = tid; i < NBUCKET_MAX; i += 256) h[i] = 0;
    __syncthreads();
    const int blk0 = blockIdx.x * EPB;
    const int nloc = min(EPB, E - blk0);
    for (int i = tid; i < nloc; i += 256) atomicAdd(&h[row[blk0 + i] >> 8], 1);
    __syncthreads();
    for (int b = tid; b < NBUCKET_MAX; b += 256) {
        int c = h[b];
        if (c) atomicAdd(&bcount[b * CPAD], c);
    }
}

// Single-block exclusive scan over NB bucket counts (NB <= 512).
__global__ void scan_buckets_kernel(const int* __restrict__ bcount, int* __restrict__ bucket_off,
                                    int* __restrict__ bcursor, int* __restrict__ offsets,
                                    int NB, int M) {
    __shared__ int buf[256];
    __shared__ int carry_s;
    if (threadIdx.x == 0) carry_s = 0;
    __syncthreads();
    for (int base = 0; base < NB; base += 256) {
        int i = base + threadIdx.x;
        int v = (i < NB) ? bcount[i * CPAD] : 0;
        buf[threadIdx.x] = v;
        __syncthreads();
        #pragma unroll
        for (int off = 1; off < 256; off <<= 1) {
            int t = (threadIdx.x >= off) ? buf[threadIdx.x - off] : 0;
            __syncthreads();
            buf[threadIdx.x] += t;
            __syncthreads();
        }
        int excl = carry_s + buf[threadIdx.x] - v;
        if (i < NB) { bucket_off[i] = excl; bcursor[i * CPAD] = excl; }
        __syncthreads();
        if (threadIdx.x == 0) carry_s += buf[255];
        __syncthreads();
    }
    if (threadIdx.x == 0) { bucket_off[NB] = carry_s; offsets[M] = carry_s; }
}

// ---------------- Two-phase multisplit ----------------

__global__ __launch_bounds__(256) void binned_scatter_kernel(
        const int* __restrict__ row, const int* __restrict__ col,
        const float* __restrict__ val, int* __restrict__ bcursor,
        int2* __restrict__ bpair, int E) {
    __shared__ int rows_s[EPB];          // 16 KB
    __shared__ int cnt[NBUCKET_MAX];
    __shared__ int base_s[NBUCKET_MAX];
    const int tid = threadIdx.x;
    const int blk0 = blockIdx.x * EPB;
    const int nloc = min(EPB, E - blk0);

    for (int i = tid; i < NBUCKET_MAX; i += 256) cnt[i] = 0;
    __syncthreads();

    for (int i = tid; i < nloc; i += 256) {
        int r = row[blk0 + i];
        rows_s[i] = r;
        atomicAdd(&cnt[r >> 8], 1);
    }
    __syncthreads();

    for (int b = tid; b < NBUCKET_MAX; b += 256) {
        int c = cnt[b];
        base_s[b] = (c > 0) ? atomicAdd(&bcursor[b * CPAD], c) : 0;
        cnt[b] = 0;  // reuse as running rank
    }
    __syncthreads();

    for (int i = tid; i < nloc; i += 256) {
        int r = rows_s[i];
        int b = r >> 8;
        int lr = atomicAdd(&cnt[b], 1);          // LDS atomic
        int pos = base_s[b] + lr;
        // pack: col in bits 0..16 (M < 131072), row_local in bits 17..24
        bpair[pos] = make_int2(col[blk0 + i] | ((r & 255) << 17), __float_as_int(val[blk0 + i]));
    }
}

// Phase B: one block per 256-node bucket; per-node offsets in-LDS, then scatter.
__global__ __launch_bounds__(256) void local_sort_kernel(
        const int2* __restrict__ bpair, const int* __restrict__ bucket_off,
        int* __restrict__ offsets, int2* __restrict__ spair, int M) {
    __shared__ int hist[256];
    __shared__ int buf[256];
    __shared__ int lcur[256];
    const int b = blockIdx.x;
    const int tid = threadIdx.x;
    const int node0 = b << 8;
    const int nn = min(256, M - node0);
    const int beg = bucket_off[b], end = bucket_off[b + 1];

    hist[tid] = 0;
    __syncthreads();
    for (int i = beg + tid; i < end; i += 256)
        atomicAdd(&hist[(bpair[i].x >> 17) & 255], 1);
    __syncthreads();

    int v = hist[tid];
    buf[tid] = v;
    __syncthreads();
    #pragma unroll
    for (int off = 1; off < 256; off <<= 1) {
        int t = (tid >= off) ? buf[tid - off] : 0;
        __syncthreads();
        buf[tid] += t;
        __syncthreads();
    }
    int o = beg + buf[tid] - v;   // exclusive
    if (tid < nn) offsets[node0 + tid] = o;
    lcur[tid] = o;
    __syncthreads();

    for (int i = beg + tid; i < end; i += 256) {
        int2 pk = bpair[i];
        int pos = atomicAdd(&lcur[(pk.x >> 17) & 255], 1);   // LDS atomic
        spair[pos] = make_int2(pk.x & 0x1FFFF, pk.y);
    }
}

// ---------------- Conversions ----------------

// W (fp32 [k][n]) -> Wt (bf16 [n][k])
__global__ __launch_bounds__(256) void convert_wt_kernel(const float* __restrict__ W,
                                                         unsigned short* __restrict__ Wt) {
    int i = blockIdx.x * 256 + threadIdx.x;   // i = n*256 + k
    int n = i >> 8, k = i & 255;
    Wt[i] = f32_to_bf16(W[k * 256 + n]);
}

// ---------------- MFMA GEMM: XWb = X @ W ----------------
// BM=128, BN=256, BK=32. 512 threads = 8 waves (2x4); wave tile 64x64 = 4x4 MFMA tiles.
// X read exactly once (nontemporal), fp32->bf16 cvt_pk fused into A-staging.
// LDS rows padded to 40 bf16 (80B) -> 2-way bank aliasing (free).

__global__ __launch_bounds__(512) void gemm_mfma_kernel(const float* __restrict__ X,
                                                        const unsigned short* __restrict__ Wt,
                                                        unsigned short* __restrict__ XWb, int M) {
    __shared__ unsigned short As[128 * 40];  // [m][k] padded
    __shared__ unsigned short Bs[256 * 40];  // [n][k] padded

    const int tid = threadIdx.x;
    const int wave = tid >> 6, lane = tid & 63;
    const int quad = lane >> 4, r = lane & 15;
    const int wr = wave >> 2, wc = wave & 3;   // 2 x 4 wave grid
    const int m0 = blockIdx.x * 128;

    const int srow = tid >> 2;        // 0..127
    const int sseg = tid & 3;         // 8-elem segment within 32-k row

    f32x4 acc[4][4] = {};

    for (int k0 = 0; k0 < D; k0 += 32) {
        // stage A: 128 rows x 32 k; fp32 nt-load + cvt_pk bf16 round
        {
            int gm = m0 + srow;
            ushort2 c0 = make_ushort2(0, 0), c1 = c0, c2 = c0, c3 = c0;
            if (gm < M) {
                const f32x4* src = (const f32x4*)(X + (size_t)gm * D + k0 + sseg * 8);
                f32x4 f0 = __builtin_nontemporal_load(src);
                f32x4 f1 = __builtin_nontemporal_load(src + 1);
                c0 = cvt2_bf16(f0[0], f0[1]); c1 = cvt2_bf16(f0[2], f0[3]);
                c2 = cvt2_bf16(f1[0], f1[1]); c3 = cvt2_bf16(f1[2], f1[3]);
            }
            unsigned short* dst = &As[srow * 40 + sseg * 8];
            *(ushort2*)(dst)     = c0;
            *(ushort2*)(dst + 2) = c1;
            *(ushort2*)(dst + 4) = c2;
            *(ushort2*)(dst + 6) = c3;
        }
        // stage B: 256 n-rows x 32 k from Wt
        #pragma unroll
        for (int h = 0; h < 2; ++h) {
            int rowB = srow + h * 128;
            uint4 w = *(const uint4*)(Wt + (size_t)rowB * D + k0 + sseg * 8);
            *(uint4*)(&Bs[rowB * 40 + sseg * 8]) = w;
        }
        __syncthreads();

        bf16x8 a[4], bb[4];
        #pragma unroll
        for (int mt = 0; mt < 4; ++mt)
            a[mt] = *(const bf16x8*)(&As[(wr * 64 + mt * 16 + r) * 40 + quad * 8]);
        #pragma unroll
        for (int nt = 0; nt < 4; ++nt)
            bb[nt] = *(const bf16x8*)(&Bs[(wc * 64 + nt * 16 + r) * 40 + quad * 8]);
        #pragma unroll
        for (int mt = 0; mt < 4; ++mt)
            #pragma unroll
            for (int nt = 0; nt < 4; ++nt)
                acc[mt][nt] = __builtin_amdgcn_mfma_f32_16x16x32_bf16(a[mt], bb[nt], acc[mt][nt], 0, 0, 0);
        __syncthreads();
    }

    // epilogue: C[row=quad*4+reg][col=lane&15] per 16x16 tile
    #pragma unroll
    for (int mt = 0; mt < 4; ++mt) {
        #pragma unroll
        for (int reg = 0; reg < 4; ++reg) {
            int gm = m0 + wr * 64 + mt * 16 + quad * 4 + reg;
            if (gm < M) {
                #pragma unroll
                for (int nt = 0; nt < 4; ++nt) {
                    int gn = wc * 64 + nt * 16 + r;
                    XWb[(size_t)gm * D + gn] = f32_to_bf16(acc[mt][nt][reg]);
                }
            }
        }
    }
}

// ---------------- Gather: out[node] = bias + sum_e val_e * XWb[col_e] ----------------
// One wave per node; lane owns 4 bf16 dims (8B nt-load per edge). Unroll-4 for MLP.
// nt on row gathers: bypass L2 allocation (rows have ~2 expected reuses/XCD),
// serve from the 256MB L3 that holds all of XWb.

__global__ __launch_bounds__(256) void gather_kernel(const unsigned short* __restrict__ XWb,
                                                     const int* __restrict__ offsets,
                                                     const int2* __restrict__ spair,
                                                     const float* __restrict__ bias,
                                                     float* __restrict__ out, int M) {
    int node = (int)((blockIdx.x * (size_t)blockDim.x + threadIdx.x) >> 6);
    int lane = threadIdx.x & 63;
    if (node >= M) return;
    int beg = offsets[node], end = offsets[node + 1];
    const unsigned short* base = XWb + lane * 4;
    float4 acc = make_float4(0.f, 0.f, 0.f, 0.f);
    int e = beg;
    for (; e + 3 < end; e += 4) {
        int2 p0 = spair[e];
        int2 p1 = spair[e + 1];
        int2 p2 = spair[e + 2];
        int2 p3 = spair[e + 3];
        u16x4 x0 = __builtin_nontemporal_load((const u16x4*)(base + (size_t)p0.x * D));
        u16x4 x1 = __builtin_nontemporal_load((const u16x4*)(base + (size_t)p1.x * D));
        u16x4 x2 = __builtin_nontemporal_load((const u16x4*)(base + (size_t)p2.x * D));
        u16x4 x3 = __builtin_nontemporal_load((const u16x4*)(base + (size_t)p3.x * D));
        float v0 = __int_as_float(p0.y), v1 = __int_as_float(p1.y);
        float v2 = __int_as_float(p2.y), v3 = __int_as_float(p3.y);
        acc.x += v0 * bf16_to_f32(x0[0]); acc.y += v0 * bf16_to_f32(x0[1]);
        acc.z += v0 * bf16_to_f32(x0[2]); acc.w += v0 * bf16_to_f32(x0[3]);
        acc.x += v1 * bf16_to_f32(x1[0]); acc.y += v1 * bf16_to_f32(x1[1]);
        acc.z += v1 * bf16_to_f32(x1[2]); acc.w += v1 * bf16_to_f32(x1[3]);
        acc.x += v2 * bf16_to_f32(x2[0]); acc.y += v2 * bf16_to_f32(x2[1]);
        acc.z += v2 * bf16_to_f32(x2[2]); acc.w += v2 * bf16_to_f32(x2[3]);
        acc.x += v3 * bf16_to_f32(x3[0]); acc.y += v3 * bf16_to_f32(x3[1]);
        acc.z += v3 * bf16_to_f32(x3[2]); acc.w += v3 * bf16_to_f32(x3[3]);
    }
    for (; e < end; ++e) {
        int2 p = spair[e];
        float v = __int_as_float(p.y);
        u16x4 x = __builtin_nontemporal_load((const u16x4*)(base + (size_t)p.x * D));
        acc.x += v * bf16_to_f32(x[0]); acc.y += v * bf16_to_f32(x[1]);
        acc.z += v * bf16_to_f32(x[2]); acc.w += v * bf16_to_f32(x[3]);
    }
    float4 b = *(const float4*)(bias + lane * 4);
    acc.x += b.x; acc.y += b.y; acc.z += b.z; acc.w += b.w;
    __builtin_nontemporal_store(*(f32x4*)&acc, (f32x4*)(out + (size_t)node * D + lane * 4));
}

extern "C" void kernel_launch(void* const* d_in, const int* in_sizes, int n_in,
                              void* d_out, int out_size, void* d_ws, size_t ws_size,
                              hipStream_t stream) {
    const float* X    = (const float*)d_in[0];
    const int*   erow = (const int*)d_in[1];
    const int*   ecol = (const int*)d_in[2];
    const float* eval = (const float*)d_in[3];
    const float* W    = (const float*)d_in[4];
    const float* bias = (const float*)d_in[5];
    float* out = (float*)d_out;

    const int M = in_sizes[0] / D;   // 100000
    const int E = in_sizes[1];       // 1600000
    const int NB = (M + 255) / 256;  // 391 buckets

    // workspace carve (~78 MB)
    char* p = (char*)d_ws;
    unsigned short* XWb = (unsigned short*)p; p += (size_t)M * D * sizeof(unsigned short);
    unsigned short* Wt  = (unsigned short*)p; p += (size_t)D * D * sizeof(unsigned short);
    int* bcount = (int*)p;      p += (size_t)NBUCKET_MAX * CPAD * sizeof(int);
    int* bcursor = (int*)p;     p += (size_t)NBUCKET_MAX * CPAD * sizeof(int);
    int* bucket_off = (int*)p;  p += (size_t)(NB + 1) * sizeof(int);
    int* offsets = (int*)p;     p += (size_t)(M + 1) * sizeof(int);
    p = (char*)(((uintptr_t)p + 15) & ~(uintptr_t)15);
    int2* bpair = (int2*)p;     p += (size_t)E * sizeof(int2);
    int2* spair = (int2*)p;     p += (size_t)E * sizeof(int2);

    hipMemsetAsync(bcount, 0, (size_t)NBUCKET_MAX * CPAD * sizeof(int), stream);
    bucket_hist_kernel<<<(E + EPB - 1) / EPB, 256, 0, stream>>>(erow, bcount, E);
    scan_buckets_kernel<<<1, 256, 0, stream>>>(bcount, bucket_off, bcursor, offsets, NB, M);
    binned_scatter_kernel<<<(E + EPB - 1) / EPB, 256, 0, stream>>>(erow, ecol, eval, bcursor, bpair, E);
    local_sort_kernel<<<NB, 256, 0, stream>>>(bpair, bucket_off, offsets, spair, M);

    convert_wt_kernel<<<(D * D) / 256, 256, 0, stream>>>(W, Wt);

    gemm_mfma_kernel<<<(M + 127) / 128, 512, 0, stream>>>(X, Wt, XWb, M);

    gather_kernel<<<(int)(((size_t)M * 64 + 255) / 256), 256, 0, stream>>>(
        XWb, offsets, spair, bias, out, M);
}

// Round 5
// 397.928 us; speedup vs baseline: 1.1531x; 1.1531x over previous
//
#include <hip/hip_runtime.h>
#include <hip/hip_bf16.h>
#include <stdint.h>

// out = A_sparse @ (X @ W) + b
// CSR build: bucket_hist (bucket-level only) -> tiny scan -> binned_scatter ->
//            local_sort (per-node offsets computed in-LDS, then in-bucket sort).
// GEMM: XWb = X @ W, MFMA 16x16x32 bf16, BM=128 BN=256 (X read exactly once),
//       fp32->bf16 via HW cvt_pk fused into A-staging, 512 threads / 8 waves (2x4),
//       LDS-transposed epilogue -> coalesced dwordx4 stores (not 64 scalar stores).
// Gather: one wave per node, plain 8B/lane row reads (L2 hit rate is load-bearing;
//         nt loads measured -50% regression in r4), unroll-4, nt out store.

#define D 256             // D_IN == D_OUT == 256
#define EPB 4096          // edges per bucketing block
#define NBUCKET_MAX 512   // supports M <= 131072
#define CPAD 16           // bucket counter padding: one counter per 64B line

typedef __attribute__((ext_vector_type(8))) short bf16x8;
typedef __attribute__((ext_vector_type(4))) float f32x4;

__device__ __forceinline__ unsigned short f32_to_bf16(float f) {
    union { float f; unsigned int u; } x; x.f = f;
    unsigned int u = x.u;
    u += 0x7fffu + ((u >> 16) & 1u);   // round-to-nearest-even
    return (unsigned short)(u >> 16);
}
__device__ __forceinline__ float bf16_to_f32(unsigned short h) {
    union { unsigned int u; float f; } x; x.u = ((unsigned int)h) << 16;
    return x.f;
}
// pairwise fp32->bf16 RNE via hip_bf16 (lowers to v_cvt_pk_bf16_f32)
__device__ __forceinline__ ushort2 cvt2_bf16(float a, float b) {
    __hip_bfloat162 h = __float22bfloat162_rn(make_float2(a, b));
    union { __hip_bfloat162 h; ushort2 u; } cv; cv.h = h;
    return cv.u;
}

// ---------------- Bucket-level histogram (LDS hist, padded global adds) ----------------

__global__ __launch_bounds__(256) void bucket_hist_kernel(const int* __restrict__ row,
                                                          int* __restrict__ bcount, int E) {
    __shared__ int h[NBUCKET_MAX];
    const int tid = threadIdx.x;
    for (int i = tid; i < NBUCKET_MAX; i += 256) h[i] = 0;
    __syncthreads();
    const int blk0 = blockIdx.x * EPB;
    const int nloc = min(EPB, E - blk0);
    for (int i = tid; i < nloc; i += 256) atomicAdd(&h[row[blk0 + i] >> 8], 1);
    __syncthreads();
    for (int b = tid; b < NBUCKET_MAX; b += 256) {
        int c = h[b];
        if (c) atomicAdd(&bcount[b * CPAD], c);
    }
}

// Single-block exclusive scan over NB bucket counts (NB <= 512).
__global__ void scan_buckets_kernel(const int* __restrict__ bcount, int* __restrict__ bucket_off,
                                    int* __restrict__ bcursor, int* __restrict__ offsets,
                                    int NB, int M) {
    __shared__ int buf[256];
    __shared__ int carry_s;
    if (threadIdx.x == 0) carry_s = 0;
    __syncthreads();
    for (int base = 0; base < NB; base += 256) {
        int i = base + threadIdx.x;
        int v = (i < NB) ? bcount[i * CPAD] : 0;
        buf[threadIdx.x] = v;
        __syncthreads();
        #pragma unroll
        for (int off = 1; off < 256; off <<= 1) {
            int t = (threadIdx.x >= off) ? buf[threadIdx.x - off] : 0;
            __syncthreads();
            buf[threadIdx.x] += t;
            __syncthreads();
        }
        int excl = carry_s + buf[threadIdx.x] - v;
        if (i < NB) { bucket_off[i] = excl; bcursor[i * CPAD] = excl; }
        __syncthreads();
        if (threadIdx.x == 0) carry_s += buf[255];
        __syncthreads();
    }
    if (threadIdx.x == 0) { bucket_off[NB] = carry_s; offsets[M] = carry_s; }
}

// ---------------- Two-phase multisplit ----------------

__global__ __launch_bounds__(256) void binned_scatter_kernel(
        const int* __restrict__ row, const int* __restrict__ col,
        const float* __restrict__ val, int* __restrict__ bcursor,
        int2* __restrict__ bpair, int E) {
    __shared__ int rows_s[EPB];          // 16 KB
    __shared__ int cnt[NBUCKET_MAX];
    __shared__ int base_s[NBUCKET_MAX];
    const int tid = threadIdx.x;
    const int blk0 = blockIdx.x * EPB;
    const int nloc = min(EPB, E - blk0);

    for (int i = tid; i < NBUCKET_MAX; i += 256) cnt[i] = 0;
    __syncthreads();

    for (int i = tid; i < nloc; i += 256) {
        int r = row[blk0 + i];
        rows_s[i] = r;
        atomicAdd(&cnt[r >> 8], 1);
    }
    __syncthreads();

    for (int b = tid; b < NBUCKET_MAX; b += 256) {
        int c = cnt[b];
        base_s[b] = (c > 0) ? atomicAdd(&bcursor[b * CPAD], c) : 0;
        cnt[b] = 0;  // reuse as running rank
    }
    __syncthreads();

    for (int i = tid; i < nloc; i += 256) {
        int r = rows_s[i];
        int b = r >> 8;
        int lr = atomicAdd(&cnt[b], 1);          // LDS atomic
        int pos = base_s[b] + lr;
        // pack: col in bits 0..16 (M < 131072), row_local in bits 17..24
        bpair[pos] = make_int2(col[blk0 + i] | ((r & 255) << 17), __float_as_int(val[blk0 + i]));
    }
}

// Phase B: one block per 256-node bucket; per-node offsets in-LDS, then scatter.
__global__ __launch_bounds__(256) void local_sort_kernel(
        const int2* __restrict__ bpair, const int* __restrict__ bucket_off,
        int* __restrict__ offsets, int2* __restrict__ spair, int M) {
    __shared__ int hist[256];
    __shared__ int buf[256];
    __shared__ int lcur[256];
    const int b = blockIdx.x;
    const int tid = threadIdx.x;
    const int node0 = b << 8;
    const int nn = min(256, M - node0);
    const int beg = bucket_off[b], end = bucket_off[b + 1];

    hist[tid] = 0;
    __syncthreads();
    for (int i = beg + tid; i < end; i += 256)
        atomicAdd(&hist[(bpair[i].x >> 17) & 255], 1);
    __syncthreads();

    int v = hist[tid];
    buf[tid] = v;
    __syncthreads();
    #pragma unroll
    for (int off = 1; off < 256; off <<= 1) {
        int t = (tid >= off) ? buf[tid - off] : 0;
        __syncthreads();
        buf[tid] += t;
        __syncthreads();
    }
    int o = beg + buf[tid] - v;   // exclusive
    if (tid < nn) offsets[node0 + tid] = o;
    lcur[tid] = o;
    __syncthreads();

    for (int i = beg + tid; i < end; i += 256) {
        int2 pk = bpair[i];
        int pos = atomicAdd(&lcur[(pk.x >> 17) & 255], 1);   // LDS atomic
        spair[pos] = make_int2(pk.x & 0x1FFFF, pk.y);
    }
}

// ---------------- Conversions ----------------

// W (fp32 [k][n]) -> Wt (bf16 [n][k])
__global__ __launch_bounds__(256) void convert_wt_kernel(const float* __restrict__ W,
                                                         unsigned short* __restrict__ Wt) {
    int i = blockIdx.x * 256 + threadIdx.x;   // i = n*256 + k
    int n = i >> 8, k = i & 255;
    Wt[i] = f32_to_bf16(W[k * 256 + n]);
}

// ---------------- MFMA GEMM: XWb = X @ W ----------------
// BM=128, BN=256, BK=32. 512 threads = 8 waves (2x4); wave tile 64x64 = 4x4 MFMA tiles.
// X read exactly once (nontemporal), fp32->bf16 cvt_pk fused into A-staging.
// LDS rows padded to 40 bf16 (80B) -> 2-way bank aliasing (free).
// Epilogue: per-wave LDS transpose (2 passes x 32 rows, wave-private region, no
// extra barriers) -> 8 coalesced dwordx4 stores/thread instead of 64 2B stores.

__global__ __launch_bounds__(512) void gemm_mfma_kernel(const float* __restrict__ X,
                                                        const unsigned short* __restrict__ Wt,
                                                        unsigned short* __restrict__ XWb, int M) {
    __shared__ union {
        struct { unsigned short As[128 * 40]; unsigned short Bs[256 * 40]; } s;  // 30720 B
        unsigned short ep[8 * 32 * 72];                                          // 36864 B
    } u;

    const int tid = threadIdx.x;
    const int wave = tid >> 6, lane = tid & 63;
    const int quad = lane >> 4, r = lane & 15;
    const int wr = wave >> 2, wc = wave & 3;   // 2 x 4 wave grid
    const int m0 = blockIdx.x * 128;

    const int srow = tid >> 2;        // 0..127
    const int sseg = tid & 3;         // 8-elem segment within 32-k row

    f32x4 acc[4][4] = {};

    for (int k0 = 0; k0 < D; k0 += 32) {
        // stage A: 128 rows x 32 k; fp32 nt-load + cvt_pk bf16 round
        {
            int gm = m0 + srow;
            ushort2 c0 = make_ushort2(0, 0), c1 = c0, c2 = c0, c3 = c0;
            if (gm < M) {
                const f32x4* src = (const f32x4*)(X + (size_t)gm * D + k0 + sseg * 8);
                f32x4 f0 = __builtin_nontemporal_load(src);
                f32x4 f1 = __builtin_nontemporal_load(src + 1);
                c0 = cvt2_bf16(f0[0], f0[1]); c1 = cvt2_bf16(f0[2], f0[3]);
                c2 = cvt2_bf16(f1[0], f1[1]); c3 = cvt2_bf16(f1[2], f1[3]);
            }
            unsigned short* dst = &u.s.As[srow * 40 + sseg * 8];
            *(ushort2*)(dst)     = c0;
            *(ushort2*)(dst + 2) = c1;
            *(ushort2*)(dst + 4) = c2;
            *(ushort2*)(dst + 6) = c3;
        }
        // stage B: 256 n-rows x 32 k from Wt
        #pragma unroll
        for (int h = 0; h < 2; ++h) {
            int rowB = srow + h * 128;
            uint4 w = *(const uint4*)(Wt + (size_t)rowB * D + k0 + sseg * 8);
            *(uint4*)(&u.s.Bs[rowB * 40 + sseg * 8]) = w;
        }
        __syncthreads();

        bf16x8 a[4], bb[4];
        #pragma unroll
        for (int mt = 0; mt < 4; ++mt)
            a[mt] = *(const bf16x8*)(&u.s.As[(wr * 64 + mt * 16 + r) * 40 + quad * 8]);
        #pragma unroll
        for (int nt = 0; nt < 4; ++nt)
            bb[nt] = *(const bf16x8*)(&u.s.Bs[(wc * 64 + nt * 16 + r) * 40 + quad * 8]);
        #pragma unroll
        for (int mt = 0; mt < 4; ++mt)
            #pragma unroll
            for (int nt = 0; nt < 4; ++nt)
                acc[mt][nt] = __builtin_amdgcn_mfma_f32_16x16x32_bf16(a[mt], bb[nt], acc[mt][nt], 0, 0, 0);
        __syncthreads();
    }
    // after the final barrier, LDS is free; each wave uses only its own ep region.

    unsigned short* w_ep = &u.ep[wave * (32 * 72)];
    #pragma unroll
    for (int p = 0; p < 2; ++p) {
        // write pass: 32 rows (mt = 2p, 2p+1) of this wave's 64x64 tile into LDS
        #pragma unroll
        for (int h = 0; h < 2; ++h) {
            int mt = 2 * p + h;
            #pragma unroll
            for (int reg = 0; reg < 4; ++reg) {
                int rl = h * 16 + quad * 4 + reg;     // 0..31
                #pragma unroll
                for (int nt = 0; nt < 4; ++nt)
                    w_ep[rl * 72 + nt * 16 + r] = f32_to_bf16(acc[mt][nt][reg]);
            }
        }
        // read pass: coalesced dwordx4 stores (wave-private region, no barrier)
        int seg = lane & 7;           // 16B segment within 128B row
        int rg  = lane >> 3;          // 0..7
        #pragma unroll
        for (int i = 0; i < 4; ++i) {
            int rl = rg + 8 * i;
            int gm = m0 + wr * 64 + p * 32 + rl;
            uint4 v = *(const uint4*)(&w_ep[rl * 72 + seg * 8]);
            if (gm < M)
                *(uint4*)(XWb + (size_t)gm * D + wc * 64 + seg * 8) = v;
        }
    }
}

// ---------------- Gather: out[node] = bias + sum_e val_e * XWb[col_e] ----------------
// One wave per node; lane owns 4 bf16 dims (8B load per edge). Unroll-4 for MLP.
// Plain (cached) row loads: L2 hit rate ~54% is load-bearing (nt = -50%, r4).

__global__ __launch_bounds__(256) void gather_kernel(const unsigned short* __restrict__ XWb,
                                                     const int* __restrict__ offsets,
                                                     const int2* __restrict__ spair,
                                                     const float* __restrict__ bias,
                                                     float* __restrict__ out, int M) {
    int node = (int)((blockIdx.x * (size_t)blockDim.x + threadIdx.x) >> 6);
    int lane = threadIdx.x & 63;
    if (node >= M) return;
    int beg = offsets[node], end = offsets[node + 1];
    const unsigned short* base = XWb + lane * 4;
    float4 acc = make_float4(0.f, 0.f, 0.f, 0.f);
    int e = beg;
    for (; e + 3 < end; e += 4) {
        int2 p0 = spair[e];
        int2 p1 = spair[e + 1];
        int2 p2 = spair[e + 2];
        int2 p3 = spair[e + 3];
        ushort4 x0 = *(const ushort4*)(base + (size_t)p0.x * D);
        ushort4 x1 = *(const ushort4*)(base + (size_t)p1.x * D);
        ushort4 x2 = *(const ushort4*)(base + (size_t)p2.x * D);
        ushort4 x3 = *(const ushort4*)(base + (size_t)p3.x * D);
        float v0 = __int_as_float(p0.y), v1 = __int_as_float(p1.y);
        float v2 = __int_as_float(p2.y), v3 = __int_as_float(p3.y);
        acc.x += v0 * bf16_to_f32(x0.x); acc.y += v0 * bf16_to_f32(x0.y);
        acc.z += v0 * bf16_to_f32(x0.z); acc.w += v0 * bf16_to_f32(x0.w);
        acc.x += v1 * bf16_to_f32(x1.x); acc.y += v1 * bf16_to_f32(x1.y);
        acc.z += v1 * bf16_to_f32(x1.z); acc.w += v1 * bf16_to_f32(x1.w);
        acc.x += v2 * bf16_to_f32(x2.x); acc.y += v2 * bf16_to_f32(x2.y);
        acc.z += v2 * bf16_to_f32(x2.z); acc.w += v2 * bf16_to_f32(x2.w);
        acc.x += v3 * bf16_to_f32(x3.x); acc.y += v3 * bf16_to_f32(x3.y);
        acc.z += v3 * bf16_to_f32(x3.z); acc.w += v3 * bf16_to_f32(x3.w);
    }
    for (; e < end; ++e) {
        int2 p = spair[e];
        float v = __int_as_float(p.y);
        ushort4 x = *(const ushort4*)(base + (size_t)p.x * D);
        acc.x += v * bf16_to_f32(x.x); acc.y += v * bf16_to_f32(x.y);
        acc.z += v * bf16_to_f32(x.z); acc.w += v * bf16_to_f32(x.w);
    }
    float4 b = *(const float4*)(bias + lane * 4);
    acc.x += b.x; acc.y += b.y; acc.z += b.z; acc.w += b.w;
    __builtin_nontemporal_store(*(f32x4*)&acc, (f32x4*)(out + (size_t)node * D + lane * 4));
}

extern "C" void kernel_launch(void* const* d_in, const int* in_sizes, int n_in,
                              void* d_out, int out_size, void* d_ws, size_t ws_size,
                              hipStream_t stream) {
    const float* X    = (const float*)d_in[0];
    const int*   erow = (const int*)d_in[1];
    const int*   ecol = (const int*)d_in[2];
    const float* eval = (const float*)d_in[3];
    const float* W    = (const float*)d_in[4];
    const float* bias = (const float*)d_in[5];
    float* out = (float*)d_out;

    const int M = in_sizes[0] / D;   // 100000
    const int E = in_sizes[1];       // 1600000
    const int NB = (M + 255) / 256;  // 391 buckets

    // workspace carve (~78 MB)
    char* p = (char*)d_ws;
    unsigned short* XWb = (unsigned short*)p; p += (size_t)M * D * sizeof(unsigned short);
    unsigned short* Wt  = (unsigned short*)p; p += (size_t)D * D * sizeof(unsigned short);
    int* bcount = (int*)p;      p += (size_t)NBUCKET_MAX * CPAD * sizeof(int);
    int* bcursor = (int*)p;     p += (size_t)NBUCKET_MAX * CPAD * sizeof(int);
    int* bucket_off = (int*)p;  p += (size_t)(NB + 1) * sizeof(int);
    int* offsets = (int*)p;     p += (size_t)(M + 1) * sizeof(int);
    p = (char*)(((uintptr_t)p + 15) & ~(uintptr_t)15);
    int2* bpair = (int2*)p;     p += (size_t)E * sizeof(int2);
    int2* spair = (int2*)p;     p += (size_t)E * sizeof(int2);

    hipMemsetAsync(bcount, 0, (size_t)NBUCKET_MAX * CPAD * sizeof(int), stream);
    bucket_hist_kernel<<<(E + EPB - 1) / EPB, 256, 0, stream>>>(erow, bcount, E);
    scan_buckets_kernel<<<1, 256, 0, stream>>>(bcount, bucket_off, bcursor, offsets, NB, M);
    binned_scatter_kernel<<<(E + EPB - 1) / EPB, 256, 0, stream>>>(erow, ecol, eval, bcursor, bpair, E);
    local_sort_kernel<<<NB, 256, 0, stream>>>(bpair, bucket_off, offsets, spair, M);

    convert_wt_kernel<<<(D * D) / 256, 256, 0, stream>>>(W, Wt);

    gemm_mfma_kernel<<<(M + 127) / 128, 512, 0, stream>>>(X, Wt, XWb, M);

    gather_kernel<<<(int)(((size_t)M * 64 + 255) / 256), 256, 0, stream>>>(
        XWb, offsets, spair, bias, out, M);
}

// Round 8
// 379.346 us; speedup vs baseline: 1.2096x; 1.0490x over previous
//
#include <hip/hip_runtime.h>
#include <hip/hip_bf16.h>
#include <stdint.h>

// out = A_sparse @ (X @ W) + b
// CSR build (2 dispatches + 32KB memset):
//   binned_scatter: bucket edges by row>>8 into CAP-padded per-bucket regions
//                   (block-private runs -> full-line writes from one XCD).
//   local_sort: one block per 256-node bucket; per-node offsets/rowend computed
//               in-LDS (bucket-local, no global scan); in-bucket counting sort.
// GEMM: XWb = X @ W, MFMA 16x16x32 bf16, BM=128 BN=256, 512 thr / 8 waves (2x4),
//       cvt_pk fp32->bf16 fused into A-staging, LDS-transposed coalesced epilogue.
//       (exact r5 body - measured passing at 397.9us)
// Gather: one wave per node, plain 8B/lane row reads (L2 hit rate load-bearing;
//         nt loads were -50% in r4), unroll-4, nt out store.

#define D 256             // D_IN == D_OUT == 256
#define EPB 4096          // edges per bucketing block (proven r3-r5)
#define NBUCKET_MAX 512   // supports M <= 131072
#define CPAD 16           // bucket counter padding: one counter per 64B line
#define CAP 6144          // per-bucket slot capacity (mean 4096, sigma ~64, +32σ)

typedef __attribute__((ext_vector_type(8))) short bf16x8;
typedef __attribute__((ext_vector_type(4))) float f32x4;

__device__ __forceinline__ unsigned short f32_to_bf16(float f) {
    union { float f; unsigned int u; } x; x.f = f;
    unsigned int u = x.u;
    u += 0x7fffu + ((u >> 16) & 1u);   // round-to-nearest-even
    return (unsigned short)(u >> 16);
}
__device__ __forceinline__ float bf16_to_f32(unsigned short h) {
    union { unsigned int u; float f; } x; x.u = ((unsigned int)h) << 16;
    return x.f;
}
// pairwise fp32->bf16 RNE via hip_bf16 (lowers to v_cvt_pk_bf16_f32)
__device__ __forceinline__ ushort2 cvt2_bf16(float a, float b) {
    __hip_bfloat162 h = __float22bfloat162_rn(make_float2(a, b));
    union { __hip_bfloat162 h; ushort2 u; } cv; cv.h = h;
    return cv.u;
}

// ---------------- Phase A: bucket multisplit into CAP-padded regions ----------------

__global__ __launch_bounds__(256) void binned_scatter_kernel(
        const int* __restrict__ row, const int* __restrict__ col,
        const float* __restrict__ val, int* __restrict__ bcursor,
        int2* __restrict__ bpair, int E) {
    __shared__ int rows_s[EPB];          // 16 KB
    __shared__ int cnt[NBUCKET_MAX];
    __shared__ int base_s[NBUCKET_MAX];
    const int tid = threadIdx.x;
    const int blk0 = blockIdx.x * EPB;
    const int nloc = min(EPB, E - blk0);

    for (int i = tid; i < NBUCKET_MAX; i += 256) cnt[i] = 0;
    __syncthreads();

    for (int i = tid; i < nloc; i += 256) {
        int r = row[blk0 + i];
        rows_s[i] = r;
        atomicAdd(&cnt[r >> 8], 1);
    }
    __syncthreads();

    for (int b = tid; b < NBUCKET_MAX; b += 256) {
        int c = cnt[b];
        base_s[b] = (c > 0) ? (b * CAP + atomicAdd(&bcursor[b * CPAD], c)) : 0;
        cnt[b] = 0;  // reuse as running rank
    }
    __syncthreads();

    for (int i = tid; i < nloc; i += 256) {
        int r = rows_s[i];
        int b = r >> 8;
        int lr = atomicAdd(&cnt[b], 1);          // LDS atomic
        int pos = base_s[b] + lr;
        // pack: col in bits 0..16 (M < 131072), row_local in bits 17..24
        bpair[pos] = make_int2(col[blk0 + i] | ((r & 255) << 17), __float_as_int(val[blk0 + i]));
    }
}

// ---------------- Phase B: per-bucket counting sort + per-node offsets ----------------

__global__ __launch_bounds__(256) void local_sort_kernel(
        const int2* __restrict__ bpair, const int* __restrict__ bcursor,
        int* __restrict__ offsets, int* __restrict__ rowend,
        int2* __restrict__ spair, int M) {
    __shared__ int hist[256];
    __shared__ int buf[256];
    __shared__ int lcur[256];
    const int b = blockIdx.x;
    const int tid = threadIdx.x;
    const int node0 = b << 8;
    const int nn = min(256, M - node0);
    const int beg = b * CAP;
    const int end = beg + bcursor[b * CPAD];

    hist[tid] = 0;
    __syncthreads();
    for (int i = beg + tid; i < end; i += 256)
        atomicAdd(&hist[(bpair[i].x >> 17) & 255], 1);
    __syncthreads();

    int v = hist[tid];
    buf[tid] = v;
    __syncthreads();
    #pragma unroll
    for (int off = 1; off < 256; off <<= 1) {
        int t = (tid >= off) ? buf[tid - off] : 0;
        __syncthreads();
        buf[tid] += t;
        __syncthreads();
    }
    int o = beg + buf[tid] - v;   // exclusive
    if (tid < nn) { offsets[node0 + tid] = o; rowend[node0 + tid] = o + v; }
    lcur[tid] = o;
    __syncthreads();

    for (int i = beg + tid; i < end; i += 256) {
        int2 pk = bpair[i];
        int pos = atomicAdd(&lcur[(pk.x >> 17) & 255], 1);   // LDS atomic
        spair[pos] = make_int2(pk.x & 0x1FFFF, pk.y);
    }
}

// ---------------- Conversions ----------------

// W (fp32 [k][n]) -> Wt (bf16 [n][k])
__global__ __launch_bounds__(256) void convert_wt_kernel(const float* __restrict__ W,
                                                         unsigned short* __restrict__ Wt) {
    int i = blockIdx.x * 256 + threadIdx.x;   // i = n*256 + k
    int n = i >> 8, k = i & 255;
    Wt[i] = f32_to_bf16(W[k * 256 + n]);
}

// ---------------- MFMA GEMM: XWb = X @ W (exact r5 body) ----------------
// BM=128, BN=256, BK=32. 512 threads = 8 waves (2x4); wave tile 64x64 = 4x4 MFMA.
// LDS rows padded to 40 bf16 (80B) -> 2-way bank aliasing (free).
// Epilogue: per-wave LDS transpose -> 8 coalesced dwordx4 stores/thread.

__global__ __launch_bounds__(512) void gemm_mfma_kernel(const float* __restrict__ X,
                                                        const unsigned short* __restrict__ Wt,
                                                        unsigned short* __restrict__ XWb, int M) {
    __shared__ union {
        struct { unsigned short As[128 * 40]; unsigned short Bs[256 * 40]; } s;  // 30720 B
        unsigned short ep[8 * 32 * 72];                                          // 36864 B
    } u;

    const int tid = threadIdx.x;
    const int wave = tid >> 6, lane = tid & 63;
    const int quad = lane >> 4, r = lane & 15;
    const int wr = wave >> 2, wc = wave & 3;   // 2 x 4 wave grid
    const int m0 = blockIdx.x * 128;

    const int srow = tid >> 2;        // 0..127
    const int sseg = tid & 3;         // 8-elem segment within 32-k row

    f32x4 acc[4][4] = {};

    for (int k0 = 0; k0 < D; k0 += 32) {
        // stage A: 128 rows x 32 k; fp32 nt-load + cvt_pk bf16 round
        {
            int gm = m0 + srow;
            ushort2 c0 = make_ushort2(0, 0), c1 = c0, c2 = c0, c3 = c0;
            if (gm < M) {
                const f32x4* src = (const f32x4*)(X + (size_t)gm * D + k0 + sseg * 8);
                f32x4 f0 = __builtin_nontemporal_load(src);
                f32x4 f1 = __builtin_nontemporal_load(src + 1);
                c0 = cvt2_bf16(f0[0], f0[1]); c1 = cvt2_bf16(f0[2], f0[3]);
                c2 = cvt2_bf16(f1[0], f1[1]); c3 = cvt2_bf16(f1[2], f1[3]);
            }
            unsigned short* dst = &u.s.As[srow * 40 + sseg * 8];
            *(ushort2*)(dst)     = c0;
            *(ushort2*)(dst + 2) = c1;
            *(ushort2*)(dst + 4) = c2;
            *(ushort2*)(dst + 6) = c3;
        }
        // stage B: 256 n-rows x 32 k from Wt
        #pragma unroll
        for (int h = 0; h < 2; ++h) {
            int rowB = srow + h * 128;
            uint4 w = *(const uint4*)(Wt + (size_t)rowB * D + k0 + sseg * 8);
            *(uint4*)(&u.s.Bs[rowB * 40 + sseg * 8]) = w;
        }
        __syncthreads();

        bf16x8 a[4], bb[4];
        #pragma unroll
        for (int mt = 0; mt < 4; ++mt)
            a[mt] = *(const bf16x8*)(&u.s.As[(wr * 64 + mt * 16 + r) * 40 + quad * 8]);
        #pragma unroll
        for (int nt = 0; nt < 4; ++nt)
            bb[nt] = *(const bf16x8*)(&u.s.Bs[(wc * 64 + nt * 16 + r) * 40 + quad * 8]);
        #pragma unroll
        for (int mt = 0; mt < 4; ++mt)
            #pragma unroll
            for (int nt = 0; nt < 4; ++nt)
                acc[mt][nt] = __builtin_amdgcn_mfma_f32_16x16x32_bf16(a[mt], bb[nt], acc[mt][nt], 0, 0, 0);
        __syncthreads();
    }
    // after the final barrier, LDS is free; each wave uses only its own ep region.

    unsigned short* w_ep = &u.ep[wave * (32 * 72)];
    #pragma unroll
    for (int p = 0; p < 2; ++p) {
        #pragma unroll
        for (int h = 0; h < 2; ++h) {
            int mt = 2 * p + h;
            #pragma unroll
            for (int reg = 0; reg < 4; ++reg) {
                int rl = h * 16 + quad * 4 + reg;     // 0..31
                #pragma unroll
                for (int nt = 0; nt < 4; ++nt)
                    w_ep[rl * 72 + nt * 16 + r] = f32_to_bf16(acc[mt][nt][reg]);
            }
        }
        int seg = lane & 7;           // 16B segment within 128B row
        int rg  = lane >> 3;          // 0..7
        #pragma unroll
        for (int i = 0; i < 4; ++i) {
            int rl = rg + 8 * i;
            int gm = m0 + wr * 64 + p * 32 + rl;
            uint4 v = *(const uint4*)(&w_ep[rl * 72 + seg * 8]);
            if (gm < M)
                *(uint4*)(XWb + (size_t)gm * D + wc * 64 + seg * 8) = v;
        }
    }
}

// ---------------- Gather: out[node] = bias + sum_e val_e * XWb[col_e] ----------------
// One wave per node; lane owns 4 bf16 dims (8B load per edge). Unroll-4 for MLP.
// Plain (cached) row loads: L2 hit rate ~54% is load-bearing (nt = -50%, r4).

__global__ __launch_bounds__(256) void gather_kernel(const unsigned short* __restrict__ XWb,
                                                     const int* __restrict__ offsets,
                                                     const int* __restrict__ rowend,
                                                     const int2* __restrict__ spair,
                                                     const float* __restrict__ bias,
                                                     float* __restrict__ out, int M) {
    int node = (int)((blockIdx.x * (size_t)blockDim.x + threadIdx.x) >> 6);
    int lane = threadIdx.x & 63;
    if (node >= M) return;
    int beg = offsets[node], end = rowend[node];
    const unsigned short* base = XWb + lane * 4;
    float4 acc = make_float4(0.f, 0.f, 0.f, 0.f);
    int e = beg;
    for (; e + 3 < end; e += 4) {
        int2 p0 = spair[e];
        int2 p1 = spair[e + 1];
        int2 p2 = spair[e + 2];
        int2 p3 = spair[e + 3];
        ushort4 x0 = *(const ushort4*)(base + (size_t)p0.x * D);
        ushort4 x1 = *(const ushort4*)(base + (size_t)p1.x * D);
        ushort4 x2 = *(const ushort4*)(base + (size_t)p2.x * D);
        ushort4 x3 = *(const ushort4*)(base + (size_t)p3.x * D);
        float v0 = __int_as_float(p0.y), v1 = __int_as_float(p1.y);
        float v2 = __int_as_float(p2.y), v3 = __int_as_float(p3.y);
        acc.x += v0 * bf16_to_f32(x0.x); acc.y += v0 * bf16_to_f32(x0.y);
        acc.z += v0 * bf16_to_f32(x0.z); acc.w += v0 * bf16_to_f32(x0.w);
        acc.x += v1 * bf16_to_f32(x1.x); acc.y += v1 * bf16_to_f32(x1.y);
        acc.z += v1 * bf16_to_f32(x1.z); acc.w += v1 * bf16_to_f32(x1.w);
        acc.x += v2 * bf16_to_f32(x2.x); acc.y += v2 * bf16_to_f32(x2.y);
        acc.z += v2 * bf16_to_f32(x2.z); acc.w += v2 * bf16_to_f32(x2.w);
        acc.x += v3 * bf16_to_f32(x3.x); acc.y += v3 * bf16_to_f32(x3.y);
        acc.z += v3 * bf16_to_f32(x3.z); acc.w += v3 * bf16_to_f32(x3.w);
    }
    for (; e < end; ++e) {
        int2 p = spair[e];
        float v = __int_as_float(p.y);
        ushort4 x = *(const ushort4*)(base + (size_t)p.x * D);
        acc.x += v * bf16_to_f32(x.x); acc.y += v * bf16_to_f32(x.y);
        acc.z += v * bf16_to_f32(x.z); acc.w += v * bf16_to_f32(x.w);
    }
    float4 b = *(const float4*)(bias + lane * 4);
    acc.x += b.x; acc.y += b.y; acc.z += b.z; acc.w += b.w;
    __builtin_nontemporal_store(*(f32x4*)&acc, (f32x4*)(out + (size_t)node * D + lane * 4));
}

extern "C" void kernel_launch(void* const* d_in, const int* in_sizes, int n_in,
                              void* d_out, int out_size, void* d_ws, size_t ws_size,
                              hipStream_t stream) {
    const float* X    = (const float*)d_in[0];
    const int*   erow = (const int*)d_in[1];
    const int*   ecol = (const int*)d_in[2];
    const float* eval = (const float*)d_in[3];
    const float* W    = (const float*)d_in[4];
    const float* bias = (const float*)d_in[5];
    float* out = (float*)d_out;

    const int M = in_sizes[0] / D;   // 100000
    const int E = in_sizes[1];       // 1600000
    const int NB = (M + 255) / 256;  // 391 buckets

    // workspace carve (~91 MB; >=117 MB proven available in r0)
    char* p = (char*)d_ws;
    unsigned short* XWb = (unsigned short*)p; p += (size_t)M * D * sizeof(unsigned short);
    unsigned short* Wt  = (unsigned short*)p; p += (size_t)D * D * sizeof(unsigned short);
    int* bcursor = (int*)p;     p += (size_t)NBUCKET_MAX * CPAD * sizeof(int);
    int* offsets = (int*)p;     p += (size_t)M * sizeof(int);
    int* rowend  = (int*)p;     p += (size_t)M * sizeof(int);
    p = (char*)(((uintptr_t)p + 15) & ~(uintptr_t)15);
    int2* bpair = (int2*)p;     p += (size_t)NB * CAP * sizeof(int2);
    int2* spair = (int2*)p;     p += (size_t)NB * CAP * sizeof(int2);

    hipMemsetAsync(bcursor, 0, (size_t)NBUCKET_MAX * CPAD * sizeof(int), stream);
    binned_scatter_kernel<<<(E + EPB - 1) / EPB, 256, 0, stream>>>(erow, ecol, eval, bcursor, bpair, E);
    local_sort_kernel<<<NB, 256, 0, stream>>>(bpair, bcursor, offsets, rowend, spair, M);

    convert_wt_kernel<<<(D * D) / 256, 256, 0, stream>>>(W, Wt);

    gemm_mfma_kernel<<<(M + 127) / 128, 512, 0, stream>>>(X, Wt, XWb, M);

    gather_kernel<<<(int)(((size_t)M * 64 + 255) / 256), 256, 0, stream>>>(
        XWb, offsets, rowend, spair, bias, out, M);
}

// Round 9
// 377.522 us; speedup vs baseline: 1.2155x; 1.0048x over previous
//
#include <hip/hip_runtime.h>
#include <hip/hip_bf16.h>
#include <stdint.h>

// out = A_sparse @ (X @ W) + b
// CSR build (2 dispatches + 32KB memset):
//   binned_scatter: bucket edges by row>>8 into CAP-padded per-bucket regions
//                   (block-private runs -> full-line writes from one XCD).
//   local_sort: one block per 256-node bucket; per-node offsets/rowend computed
//               in-LDS (bucket-local, no global scan); in-bucket counting sort.
// GEMM: XWb = X @ W, MFMA 16x16x32 bf16, BM=128 BN=256, 512 thr / 8 waves (2x4),
//       cvt_pk fp32->bf16 fused into A-staging, LDS-transposed coalesced epilogue.
//       X loads are PLAIN CACHED (r4 evidence: nt loads run ~2.7TB/s vs 4+ cached).
// Gather: one wave per node, plain 8B/lane row reads (L2 hit rate load-bearing),
//         unroll-8 for MLP (mean degree 16), nt out store.

#define D 256             // D_IN == D_OUT == 256
#define EPB 4096          // edges per bucketing block (proven r3-r5,r8)
#define NBUCKET_MAX 512   // supports M <= 131072
#define CPAD 16           // bucket counter padding: one counter per 64B line
#define CAP 6144          // per-bucket slot capacity (mean 4096, sigma ~64, +32σ)

typedef __attribute__((ext_vector_type(8))) short bf16x8;
typedef __attribute__((ext_vector_type(4))) float f32x4;

__device__ __forceinline__ unsigned short f32_to_bf16(float f) {
    union { float f; unsigned int u; } x; x.f = f;
    unsigned int u = x.u;
    u += 0x7fffu + ((u >> 16) & 1u);   // round-to-nearest-even
    return (unsigned short)(u >> 16);
}
__device__ __forceinline__ float bf16_to_f32(unsigned short h) {
    union { unsigned int u; float f; } x; x.u = ((unsigned int)h) << 16;
    return x.f;
}
// pairwise fp32->bf16 RNE via hip_bf16 (lowers to v_cvt_pk_bf16_f32)
__device__ __forceinline__ ushort2 cvt2_bf16(float a, float b) {
    __hip_bfloat162 h = __float22bfloat162_rn(make_float2(a, b));
    union { __hip_bfloat162 h; ushort2 u; } cv; cv.h = h;
    return cv.u;
}

// ---------------- Phase A: bucket multisplit into CAP-padded regions ----------------

__global__ __launch_bounds__(256) void binned_scatter_kernel(
        const int* __restrict__ row, const int* __restrict__ col,
        const float* __restrict__ val, int* __restrict__ bcursor,
        int2* __restrict__ bpair, int E) {
    __shared__ int rows_s[EPB];          // 16 KB
    __shared__ int cnt[NBUCKET_MAX];
    __shared__ int base_s[NBUCKET_MAX];
    const int tid = threadIdx.x;
    const int blk0 = blockIdx.x * EPB;
    const int nloc = min(EPB, E - blk0);

    for (int i = tid; i < NBUCKET_MAX; i += 256) cnt[i] = 0;
    __syncthreads();

    for (int i = tid; i < nloc; i += 256) {
        int r = row[blk0 + i];
        rows_s[i] = r;
        atomicAdd(&cnt[r >> 8], 1);
    }
    __syncthreads();

    for (int b = tid; b < NBUCKET_MAX; b += 256) {
        int c = cnt[b];
        base_s[b] = (c > 0) ? (b * CAP + atomicAdd(&bcursor[b * CPAD], c)) : 0;
        cnt[b] = 0;  // reuse as running rank
    }
    __syncthreads();

    for (int i = tid; i < nloc; i += 256) {
        int r = rows_s[i];
        int b = r >> 8;
        int lr = atomicAdd(&cnt[b], 1);          // LDS atomic
        int pos = base_s[b] + lr;
        // pack: col in bits 0..16 (M < 131072), row_local in bits 17..24
        bpair[pos] = make_int2(col[blk0 + i] | ((r & 255) << 17), __float_as_int(val[blk0 + i]));
    }
}

// ---------------- Phase B: per-bucket counting sort + per-node offsets ----------------

__global__ __launch_bounds__(256) void local_sort_kernel(
        const int2* __restrict__ bpair, const int* __restrict__ bcursor,
        int* __restrict__ offsets, int* __restrict__ rowend,
        int2* __restrict__ spair, int M) {
    __shared__ int hist[256];
    __shared__ int buf[256];
    __shared__ int lcur[256];
    const int b = blockIdx.x;
    const int tid = threadIdx.x;
    const int node0 = b << 8;
    const int nn = min(256, M - node0);
    const int beg = b * CAP;
    const int end = beg + bcursor[b * CPAD];

    hist[tid] = 0;
    __syncthreads();
    for (int i = beg + tid; i < end; i += 256)
        atomicAdd(&hist[(bpair[i].x >> 17) & 255], 1);
    __syncthreads();

    int v = hist[tid];
    buf[tid] = v;
    __syncthreads();
    #pragma unroll
    for (int off = 1; off < 256; off <<= 1) {
        int t = (tid >= off) ? buf[tid - off] : 0;
        __syncthreads();
        buf[tid] += t;
        __syncthreads();
    }
    int o = beg + buf[tid] - v;   // exclusive
    if (tid < nn) { offsets[node0 + tid] = o; rowend[node0 + tid] = o + v; }
    lcur[tid] = o;
    __syncthreads();

    for (int i = beg + tid; i < end; i += 256) {
        int2 pk = bpair[i];
        int pos = atomicAdd(&lcur[(pk.x >> 17) & 255], 1);   // LDS atomic
        spair[pos] = make_int2(pk.x & 0x1FFFF, pk.y);
    }
}

// ---------------- Conversions ----------------

// W (fp32 [k][n]) -> Wt (bf16 [n][k])
__global__ __launch_bounds__(256) void convert_wt_kernel(const float* __restrict__ W,
                                                         unsigned short* __restrict__ Wt) {
    int i = blockIdx.x * 256 + threadIdx.x;   // i = n*256 + k
    int n = i >> 8, k = i & 255;
    Wt[i] = f32_to_bf16(W[k * 256 + n]);
}

// ---------------- MFMA GEMM: XWb = X @ W ----------------
// BM=128, BN=256, BK=32. 512 threads = 8 waves (2x4); wave tile 64x64 = 4x4 MFMA.
// LDS rows padded to 40 bf16 (80B) -> 2-way bank aliasing (free).
// Epilogue: per-wave LDS transpose -> 8 coalesced dwordx4 stores/thread.

__global__ __launch_bounds__(512) void gemm_mfma_kernel(const float* __restrict__ X,
                                                        const unsigned short* __restrict__ Wt,
                                                        unsigned short* __restrict__ XWb, int M) {
    __shared__ union {
        struct { unsigned short As[128 * 40]; unsigned short Bs[256 * 40]; } s;  // 30720 B
        unsigned short ep[8 * 32 * 72];                                          // 36864 B
    } u;

    const int tid = threadIdx.x;
    const int wave = tid >> 6, lane = tid & 63;
    const int quad = lane >> 4, r = lane & 15;
    const int wr = wave >> 2, wc = wave & 3;   // 2 x 4 wave grid
    const int m0 = blockIdx.x * 128;

    const int srow = tid >> 2;        // 0..127
    const int sseg = tid & 3;         // 8-elem segment within 32-k row

    f32x4 acc[4][4] = {};

    for (int k0 = 0; k0 < D; k0 += 32) {
        // stage A: 128 rows x 32 k; plain cached fp32 load + cvt_pk bf16 round
        {
            int gm = m0 + srow;
            ushort2 c0 = make_ushort2(0, 0), c1 = c0, c2 = c0, c3 = c0;
            if (gm < M) {
                const f32x4* src = (const f32x4*)(X + (size_t)gm * D + k0 + sseg * 8);
                f32x4 f0 = src[0];
                f32x4 f1 = src[1];
                c0 = cvt2_bf16(f0[0], f0[1]); c1 = cvt2_bf16(f0[2], f0[3]);
                c2 = cvt2_bf16(f1[0], f1[1]); c3 = cvt2_bf16(f1[2], f1[3]);
            }
            unsigned short* dst = &u.s.As[srow * 40 + sseg * 8];
            *(ushort2*)(dst)     = c0;
            *(ushort2*)(dst + 2) = c1;
            *(ushort2*)(dst + 4) = c2;
            *(ushort2*)(dst + 6) = c3;
        }
        // stage B: 256 n-rows x 32 k from Wt
        #pragma unroll
        for (int h = 0; h < 2; ++h) {
            int rowB = srow + h * 128;
            uint4 w = *(const uint4*)(Wt + (size_t)rowB * D + k0 + sseg * 8);
            *(uint4*)(&u.s.Bs[rowB * 40 + sseg * 8]) = w;
        }
        __syncthreads();

        bf16x8 a[4], bb[4];
        #pragma unroll
        for (int mt = 0; mt < 4; ++mt)
            a[mt] = *(const bf16x8*)(&u.s.As[(wr * 64 + mt * 16 + r) * 40 + quad * 8]);
        #pragma unroll
        for (int nt = 0; nt < 4; ++nt)
            bb[nt] = *(const bf16x8*)(&u.s.Bs[(wc * 64 + nt * 16 + r) * 40 + quad * 8]);
        #pragma unroll
        for (int mt = 0; mt < 4; ++mt)
            #pragma unroll
            for (int nt = 0; nt < 4; ++nt)
                acc[mt][nt] = __builtin_amdgcn_mfma_f32_16x16x32_bf16(a[mt], bb[nt], acc[mt][nt], 0, 0, 0);
        __syncthreads();
    }
    // after the final barrier, LDS is free; each wave uses only its own ep region.

    unsigned short* w_ep = &u.ep[wave * (32 * 72)];
    #pragma unroll
    for (int p = 0; p < 2; ++p) {
        #pragma unroll
        for (int h = 0; h < 2; ++h) {
            int mt = 2 * p + h;
            #pragma unroll
            for (int reg = 0; reg < 4; ++reg) {
                int rl = h * 16 + quad * 4 + reg;     // 0..31
                #pragma unroll
                for (int nt = 0; nt < 4; ++nt)
                    w_ep[rl * 72 + nt * 16 + r] = f32_to_bf16(acc[mt][nt][reg]);
            }
        }
        int seg = lane & 7;           // 16B segment within 128B row
        int rg  = lane >> 3;          // 0..7
        #pragma unroll
        for (int i = 0; i < 4; ++i) {
            int rl = rg + 8 * i;
            int gm = m0 + wr * 64 + p * 32 + rl;
            uint4 v = *(const uint4*)(&w_ep[rl * 72 + seg * 8]);
            if (gm < M)
                *(uint4*)(XWb + (size_t)gm * D + wc * 64 + seg * 8) = v;
        }
    }
}

// ---------------- Gather: out[node] = bias + sum_e val_e * XWb[col_e] ----------------
// One wave per node; lane owns 4 bf16 dims (8B load per edge). Unroll-8 for MLP
// (mean degree 16 -> 2 main iterations). Plain cached row loads (nt = -50%, r4).

__global__ __launch_bounds__(256) void gather_kernel(const unsigned short* __restrict__ XWb,
                                                     const int* __restrict__ offsets,
                                                     const int* __restrict__ rowend,
                                                     const int2* __restrict__ spair,
                                                     const float* __restrict__ bias,
                                                     float* __restrict__ out, int M) {
    int node = (int)((blockIdx.x * (size_t)blockDim.x + threadIdx.x) >> 6);
    int lane = threadIdx.x & 63;
    if (node >= M) return;
    int beg = offsets[node], end = rowend[node];
    const unsigned short* base = XWb + lane * 4;
    float4 acc = make_float4(0.f, 0.f, 0.f, 0.f);
    int e = beg;
    for (; e + 7 < end; e += 8) {
        int2 p0 = spair[e],     p1 = spair[e + 1], p2 = spair[e + 2], p3 = spair[e + 3];
        int2 p4 = spair[e + 4], p5 = spair[e + 5], p6 = spair[e + 6], p7 = spair[e + 7];
        ushort4 x0 = *(const ushort4*)(base + (size_t)p0.x * D);
        ushort4 x1 = *(const ushort4*)(base + (size_t)p1.x * D);
        ushort4 x2 = *(const ushort4*)(base + (size_t)p2.x * D);
        ushort4 x3 = *(const ushort4*)(base + (size_t)p3.x * D);
        ushort4 x4 = *(const ushort4*)(base + (size_t)p4.x * D);
        ushort4 x5 = *(const ushort4*)(base + (size_t)p5.x * D);
        ushort4 x6 = *(const ushort4*)(base + (size_t)p6.x * D);
        ushort4 x7 = *(const ushort4*)(base + (size_t)p7.x * D);
        float v0 = __int_as_float(p0.y), v1 = __int_as_float(p1.y);
        float v2 = __int_as_float(p2.y), v3 = __int_as_float(p3.y);
        float v4 = __int_as_float(p4.y), v5 = __int_as_float(p5.y);
        float v6 = __int_as_float(p6.y), v7 = __int_as_float(p7.y);
        acc.x += v0 * bf16_to_f32(x0.x); acc.y += v0 * bf16_to_f32(x0.y);
        acc.z += v0 * bf16_to_f32(x0.z); acc.w += v0 * bf16_to_f32(x0.w);
        acc.x += v1 * bf16_to_f32(x1.x); acc.y += v1 * bf16_to_f32(x1.y);
        acc.z += v1 * bf16_to_f32(x1.z); acc.w += v1 * bf16_to_f32(x1.w);
        acc.x += v2 * bf16_to_f32(x2.x); acc.y += v2 * bf16_to_f32(x2.y);
        acc.z += v2 * bf16_to_f32(x2.z); acc.w += v2 * bf16_to_f32(x2.w);
        acc.x += v3 * bf16_to_f32(x3.x); acc.y += v3 * bf16_to_f32(x3.y);
        acc.z += v3 * bf16_to_f32(x3.z); acc.w += v3 * bf16_to_f32(x3.w);
        acc.x += v4 * bf16_to_f32(x4.x); acc.y += v4 * bf16_to_f32(x4.y);
        acc.z += v4 * bf16_to_f32(x4.z); acc.w += v4 * bf16_to_f32(x4.w);
        acc.x += v5 * bf16_to_f32(x5.x); acc.y += v5 * bf16_to_f32(x5.y);
        acc.z += v5 * bf16_to_f32(x5.z); acc.w += v5 * bf16_to_f32(x5.w);
        acc.x += v6 * bf16_to_f32(x6.x); acc.y += v6 * bf16_to_f32(x6.y);
        acc.z += v6 * bf16_to_f32(x6.z); acc.w += v6 * bf16_to_f32(x6.w);
        acc.x += v7 * bf16_to_f32(x7.x); acc.y += v7 * bf16_to_f32(x7.y);
        acc.z += v7 * bf16_to_f32(x7.z); acc.w += v7 * bf16_to_f32(x7.w);
    }
    for (; e + 3 < end; e += 4) {
        int2 p0 = spair[e], p1 = spair[e + 1], p2 = spair[e + 2], p3 = spair[e + 3];
        ushort4 x0 = *(const ushort4*)(base + (size_t)p0.x * D);
        ushort4 x1 = *(const ushort4*)(base + (size_t)p1.x * D);
        ushort4 x2 = *(const ushort4*)(base + (size_t)p2.x * D);
        ushort4 x3 = *(const ushort4*)(base + (size_t)p3.x * D);
        float v0 = __int_as_float(p0.y), v1 = __int_as_float(p1.y);
        float v2 = __int_as_float(p2.y), v3 = __int_as_float(p3.y);
        acc.x += v0 * bf16_to_f32(x0.x); acc.y += v0 * bf16_to_f32(x0.y);
        acc.z += v0 * bf16_to_f32(x0.z); acc.w += v0 * bf16_to_f32(x0.w);
        acc.x += v1 * bf16_to_f32(x1.x); acc.y += v1 * bf16_to_f32(x1.y);
        acc.z += v1 * bf16_to_f32(x1.z); acc.w += v1 * bf16_to_f32(x1.w);
        acc.x += v2 * bf16_to_f32(x2.x); acc.y += v2 * bf16_to_f32(x2.y);
        acc.z += v2 * bf16_to_f32(x2.z); acc.w += v2 * bf16_to_f32(x2.w);
        acc.x += v3 * bf16_to_f32(x3.x); acc.y += v3 * bf16_to_f32(x3.y);
        acc.z += v3 * bf16_to_f32(x3.z); acc.w += v3 * bf16_to_f32(x3.w);
    }
    for (; e < end; ++e) {
        int2 p = spair[e];
        float v = __int_as_float(p.y);
        ushort4 x = *(const ushort4*)(base + (size_t)p.x * D);
        acc.x += v * bf16_to_f32(x.x); acc.y += v * bf16_to_f32(x.y);
        acc.z += v * bf16_to_f32(x.z); acc.w += v * bf16_to_f32(x.w);
    }
    float4 b = *(const float4*)(bias + lane * 4);
    acc.x += b.x; acc.y += b.y; acc.z += b.z; acc.w += b.w;
    __builtin_nontemporal_store(*(f32x4*)&acc, (f32x4*)(out + (size_t)node * D + lane * 4));
}

extern "C" void kernel_launch(void* const* d_in, const int* in_sizes, int n_in,
                              void* d_out, int out_size, void* d_ws, size_t ws_size,
                              hipStream_t stream) {
    const float* X    = (const float*)d_in[0];
    const int*   erow = (const int*)d_in[1];
    const int*   ecol = (const int*)d_in[2];
    const float* eval = (const float*)d_in[3];
    const float* W    = (const float*)d_in[4];
    const float* bias = (const float*)d_in[5];
    float* out = (float*)d_out;

    const int M = in_sizes[0] / D;   // 100000
    const int E = in_sizes[1];       // 1600000
    const int NB = (M + 255) / 256;  // 391 buckets

    // workspace carve (~91 MB; >=117 MB proven available in r0)
    char* p = (char*)d_ws;
    unsigned short* XWb = (unsigned short*)p; p += (size_t)M * D * sizeof(unsigned short);
    unsigned short* Wt  = (unsigned short*)p; p += (size_t)D * D * sizeof(unsigned short);
    int* bcursor = (int*)p;     p += (size_t)NBUCKET_MAX * CPAD * sizeof(int);
    int* offsets = (int*)p;     p += (size_t)M * sizeof(int);
    int* rowend  = (int*)p;     p += (size_t)M * sizeof(int);
    p = (char*)(((uintptr_t)p + 15) & ~(uintptr_t)15);
    int2* bpair = (int2*)p;     p += (size_t)NB * CAP * sizeof(int2);
    int2* spair = (int2*)p;     p += (size_t)NB * CAP * sizeof(int2);

    hipMemsetAsync(bcursor, 0, (size_t)NBUCKET_MAX * CPAD * sizeof(int), stream);
    binned_scatter_kernel<<<(E + EPB - 1) / EPB, 256, 0, stream>>>(erow, ecol, eval, bcursor, bpair, E);
    local_sort_kernel<<<NB, 256, 0, stream>>>(bpair, bcursor, offsets, rowend, spair, M);

    convert_wt_kernel<<<(D * D) / 256, 256, 0, stream>>>(W, Wt);

    gemm_mfma_kernel<<<(M + 127) / 128, 512, 0, stream>>>(X, Wt, XWb, M);

    gather_kernel<<<(int)(((size_t)M * 64 + 255) / 256), 256, 0, stream>>>(
        XWb, offsets, rowend, spair, bias, out, M);
}